// Round 1
// baseline (510.525 us; speedup 1.0000x reference)
//
#include <hip/hip_runtime.h>
#include <stdint.h>
#include <stdio.h>

#define NROWS 8192
#define DDIM 256

typedef __attribute__((ext_vector_type(8))) __bf16 bf16x8;
typedef __attribute__((ext_vector_type(4))) float f32x4;
typedef __attribute__((address_space(3))) uint32_t as3u32;
typedef __attribute__((address_space(1))) uint32_t as1u32;

__device__ __forceinline__ void glds16(const void* g, void* l) {
  __builtin_amdgcn_global_load_lds((const as1u32*)g, (as3u32*)l, 16, 0, 0);
}

// round-to-nearest-even f32 -> bf16 bits
__device__ __forceinline__ ushort f2b(float f) {
  uint32_t u = __float_as_uint(f);
  return (ushort)((u + 0x7FFFu + ((u >> 16) & 1u)) >> 16);
}

// ---------------- k1: inv_deg[i] = 1 / sum_k A[i,k] ----------------
__global__ __launch_bounds__(256) void degree_kernel(const float* __restrict__ A,
                                                     float* __restrict__ inv_deg) {
  const int row = blockIdx.x * 4 + (threadIdx.x >> 6);
  const int lane = threadIdx.x & 63;
  const float4* r4 = (const float4*)(A + (size_t)row * NROWS);
  float s = 0.f;
#pragma unroll
  for (int i = 0; i < 32; ++i) {
    float4 v = r4[lane + (i << 6)];
    s += (v.x + v.y) + (v.z + v.w);
  }
#pragma unroll
  for (int o = 32; o > 0; o >>= 1) s += __shfl_xor(s, o, 64);
  if (lane == 0) inv_deg[row] = 1.0f / s;
}

// ---------------- k2: dst[c][k] = bf16(src[k][c] * scale[k])  (src is [K][256] f32)
__global__ __launch_bounds__(256) void transpose_scale_kernel(const float* __restrict__ src,
                                                              const float* __restrict__ scale,
                                                              ushort* __restrict__ dst, int K) {
  __shared__ ushort tile[64 * 256];
  const int k0 = blockIdx.x * 64;
  const int w = threadIdx.x >> 6;
  const int lane = threadIdx.x & 63;
#pragma unroll
  for (int i = 0; i < 16; ++i) {
    const int r = w * 16 + i;
    float4 v = *(const float4*)(src + (size_t)(k0 + r) * DDIM + lane * 4);
    const float sc = scale ? scale[k0 + r] : 1.0f;
    ushort4 b;
    b.x = f2b(v.x * sc); b.y = f2b(v.y * sc);
    b.z = f2b(v.z * sc); b.w = f2b(v.w * sc);
    *(ushort4*)&tile[r * 256 + lane * 4] = b;
  }
  __syncthreads();
  const int c = threadIdx.x;  // 0..255: one output row (column of src)
  ushort* drow = dst + (size_t)c * K + k0;
#pragma unroll
  for (int s = 0; s < 8; ++s) {
    uint32_t p[4];
#pragma unroll
    for (int j = 0; j < 4; ++j) {
      uint32_t lo = tile[(s * 8 + 2 * j + 0) * 256 + c];
      uint32_t hi = tile[(s * 8 + 2 * j + 1) * 256 + c];
      p[j] = lo | (hi << 16);
    }
    uint4 u; u.x = p[0]; u.y = p[1]; u.z = p[2]; u.w = p[3];
    *(uint4*)(drow + s * 8) = u;
  }
}

// ---------------- k3/k4: C[m0:m0+32, 0:256] (+= over k-split) = Am(+Am2) @ Bt^T ----
// Am: [8192][lda] f32 (bf16-converted on the fly). Bt: [256][K] bf16 (pre-transposed).
// BM=32, BN=256 (full N -> A read exactly once), BK=32, 8 waves, wave w owns cols w*32..+31.
// B staged via global_load_lds with pre-swizzled global source (rule #21); A reg-staged.
// Swizzle: 16B-chunk index ^= ((row>>1)&3)  -> 2-way max bank aliasing (free, m136).
__global__ __launch_bounds__(512, 4) void gemm_bf16_kernel(
    const float* __restrict__ Am, const float* __restrict__ Am2, int lda,
    const ushort* __restrict__ Bt, int K, int klen, int nsplit,
    const float* __restrict__ rowscale, const float* __restrict__ bias,
    int do_relu, float* __restrict__ C) {
  __shared__ ushort Asm[2][32 * 32];    // 2 x 2 KB
  __shared__ ushort Bsm[2][256 * 32];   // 2 x 16 KB

  const int tid = threadIdx.x;
  const int lane = tid & 63;
  const int w = tid >> 6;

  int ks, mb;
  if (nsplit == 2) { ks = blockIdx.x & 1; mb = blockIdx.x >> 1; }  // ks tracks XCD parity
  else             { ks = 0;             mb = blockIdx.x; }
  const int kstart = ks * klen;
  const int m0 = mb * 32;
  float* Cp = C + (size_t)ks * ((size_t)NROWS * DDIM);

  f32x4 acc[2][2] = {};
  const int NT = klen >> 5;

  // A staging (threads 0..255): one float4 per thread per tile
  const int arow = tid >> 3;
  const int aseg = tid & 7;
  const float* ag  = Am  + (size_t)(m0 + arow) * lda + kstart + aseg * 4;
  const float* ag2 = Am2 ? (Am2 + (size_t)(m0 + arow) * lda + kstart + aseg * 4) : nullptr;
  const int awoff = arow * 32 + ((((aseg >> 1) ^ ((arow >> 1) & 3)) << 3) | ((aseg & 1) << 2));

  // B staging: wave w stages chunks 2w, 2w+1 (1 KB each = 16 cols x 64 B)
  const int bch0 = w * 2;
  const int bq = lane >> 2;
  const int bswz = (lane & 3) ^ ((lane >> 3) & 3);  // pre-swizzled source chunk
  const char* bg0 = (const char*)Bt + (size_t)(bch0 * 16 + bq) * ((size_t)K * 2)
                    + (size_t)kstart * 2 + bswz * 16;
  const char* bg1 = bg0 + (size_t)16 * ((size_t)K * 2);

  // fragment read offsets (ushort units), swizzled
  const int fr = lane & 15;
  const int fsw = (fr >> 1) & 3;
  const int fch = (lane >> 4) ^ fsw;
  const int aoff0 = (fr) * 32 + (fch << 3);
  const int aoff1 = (16 + fr) * 32 + (fch << 3);
  const int boff0 = (w * 32 + fr) * 32 + (fch << 3);
  const int boff1 = (w * 32 + 16 + fr) * 32 + (fch << 3);

  // prologue: stage tile 0 into buffer 0
  if (tid < 256) {
    float4 v = *(const float4*)ag;
    if (ag2) { float4 v2 = *(const float4*)ag2; v.x += v2.x; v.y += v2.y; v.z += v2.z; v.w += v2.w; }
    ushort4 b; b.x = f2b(v.x); b.y = f2b(v.y); b.z = f2b(v.z); b.w = f2b(v.w);
    *(ushort4*)&Asm[0][awoff] = b;
  }
  glds16(bg0, &Bsm[0][(bch0 + 0) * 512]);
  glds16(bg1, &Bsm[0][(bch0 + 1) * 512]);

  int cur = 0;
  for (int t = 0; t < NT; ++t) {
    __syncthreads();
    const bool pf = (t + 1 < NT);
    float4 av, av2;
    if (pf) {
      if (tid < 256) {
        av = *(const float4*)(ag + (t + 1) * 32);
        if (ag2) av2 = *(const float4*)(ag2 + (t + 1) * 32);
      }
      glds16(bg0 + (size_t)(t + 1) * 64, &Bsm[cur ^ 1][(bch0 + 0) * 512]);
      glds16(bg1 + (size_t)(t + 1) * 64, &Bsm[cur ^ 1][(bch0 + 1) * 512]);
    }

    uint4 a0 = *(const uint4*)&Asm[cur][aoff0];
    uint4 a1 = *(const uint4*)&Asm[cur][aoff1];
    uint4 b0 = *(const uint4*)&Bsm[cur][boff0];
    uint4 b1 = *(const uint4*)&Bsm[cur][boff1];
    bf16x8 fa0 = __builtin_bit_cast(bf16x8, a0);
    bf16x8 fa1 = __builtin_bit_cast(bf16x8, a1);
    bf16x8 fb0 = __builtin_bit_cast(bf16x8, b0);
    bf16x8 fb1 = __builtin_bit_cast(bf16x8, b1);
    acc[0][0] = __builtin_amdgcn_mfma_f32_16x16x32_bf16(fa0, fb0, acc[0][0], 0, 0, 0);
    acc[0][1] = __builtin_amdgcn_mfma_f32_16x16x32_bf16(fa0, fb1, acc[0][1], 0, 0, 0);
    acc[1][0] = __builtin_amdgcn_mfma_f32_16x16x32_bf16(fa1, fb0, acc[1][0], 0, 0, 0);
    acc[1][1] = __builtin_amdgcn_mfma_f32_16x16x32_bf16(fa1, fb1, acc[1][1], 0, 0, 0);

    if (pf && tid < 256) {
      float4 v = av;
      if (ag2) { v.x += av2.x; v.y += av2.y; v.z += av2.z; v.w += av2.w; }
      ushort4 b; b.x = f2b(v.x); b.y = f2b(v.y); b.z = f2b(v.z); b.w = f2b(v.w);
      *(ushort4*)&Asm[cur ^ 1][awoff] = b;
    }
    cur ^= 1;
  }

  // epilogue: D layout col=lane&15, row=(lane>>4)*4+reg  [measured m89]
#pragma unroll
  for (int m = 0; m < 2; ++m)
#pragma unroll
    for (int n = 0; n < 2; ++n) {
      const int col = w * 32 + n * 16 + fr;
      const float bv = bias ? bias[col] : 0.f;
#pragma unroll
      for (int r = 0; r < 4; ++r) {
        const int row = m0 + m * 16 + (lane >> 4) * 4 + r;
        float x = acc[m][n][r];
        if (rowscale) x *= rowscale[row];
        x += bv;
        if (do_relu) x = fmaxf(x, 0.f);
        Cp[(size_t)row * DDIM + col] = x;
      }
    }
}

extern "C" void kernel_launch(void* const* d_in, const int* in_sizes, int n_in,
                              void* d_out, int out_size, void* d_ws, size_t ws_size,
                              hipStream_t stream) {
  const float* x      = (const float*)d_in[0];
  const float* adj    = (const float*)d_in[1];
  const float* weight = (const float*)d_in[2];
  const float* bias   = (const float*)d_in[3];
  float* out = (float*)d_out;

  char* ws = (char*)d_ws;
  const size_t h_bytes  = 2ull * NROWS * DDIM * 4;            // 16 MB: 2 k-split partials
  const size_t yt_bytes = (size_t)DDIM * NROWS * 2;           // 4 MB
  const size_t wt_bytes = (size_t)DDIM * DDIM * 2;            // 128 KB
  float*  h       = (float*)ws;
  ushort* Yt      = (ushort*)(ws + h_bytes);
  ushort* Wt      = (ushort*)(ws + h_bytes + yt_bytes);
  float*  inv_deg = (float*)(ws + h_bytes + yt_bytes + wt_bytes);
  const size_t need = h_bytes + yt_bytes + wt_bytes + (size_t)NROWS * 4;
  if (ws_size < need) { fprintf(stderr, "ws too small: %zu < %zu\n", ws_size, need); return; }

  // k1: degrees -> inv_deg
  degree_kernel<<<NROWS / 4, 256, 0, stream>>>(adj, inv_deg);
  // k2a: Yt[c][k] = bf16(x[k][c] * inv_deg[k]);  k2b: Wt[n][d] = bf16(W[d][n])
  transpose_scale_kernel<<<NROWS / 64, 256, 0, stream>>>(x, inv_deg, Yt, NROWS);
  transpose_scale_kernel<<<DDIM / 64, 256, 0, stream>>>(weight, nullptr, Wt, DDIM);
  // k3: h_part[ks] = inv_deg[i] * (A @ Yt^T) over k-half ks   (512 blocks = 2/CU)
  gemm_bf16_kernel<<<dim3(512), 512, 0, stream>>>(adj, nullptr, NROWS, Yt, NROWS,
                                                  NROWS / 2, 2, inv_deg, nullptr, 0, h);
  // k4: out = relu((h0+h1) @ Wt^T + bias)
  gemm_bf16_kernel<<<dim3(256), 512, 0, stream>>>(h, h + (size_t)NROWS * DDIM, DDIM, Wt, DDIM,
                                                  DDIM, 1, nullptr, bias, 1, out);
}

// Round 2
// 472.083 us; speedup vs baseline: 1.0814x; 1.0814x over previous
//
#include <hip/hip_runtime.h>
#include <stdint.h>
#include <stdio.h>

#define NROWS 8192
#define DDIM 256

typedef __attribute__((ext_vector_type(8))) __bf16 bf16x8;
typedef __attribute__((ext_vector_type(4))) float f32x4;
typedef __attribute__((address_space(3))) uint32_t as3u32;
typedef __attribute__((address_space(1))) uint32_t as1u32;

__device__ __forceinline__ void glds16(const void* g, void* l) {
  __builtin_amdgcn_global_load_lds((const as1u32*)g, (as3u32*)l, 16, 0, 0);
}

// round-to-nearest-even f32 -> bf16 bits
__device__ __forceinline__ ushort f2b(float f) {
  uint32_t u = __float_as_uint(f);
  return (ushort)((u + 0x7FFFu + ((u >> 16) & 1u)) >> 16);
}

// ---------------- k1: inv_deg[i] = 1/sum_k A[i,k]; Ab = bf16(A) ----------------
__global__ __launch_bounds__(256) void degree_cast_kernel(const float* __restrict__ A,
                                                          ushort* __restrict__ Ab,
                                                          float* __restrict__ inv_deg) {
  const int row = blockIdx.x * 4 + (threadIdx.x >> 6);
  const int lane = threadIdx.x & 63;
  const float4* r4 = (const float4*)(A + (size_t)row * NROWS);
  ushort* wr = Ab + (size_t)row * NROWS;
  float s = 0.f;
#pragma unroll
  for (int i = 0; i < 32; ++i) {
    float4 v = r4[lane + (i << 6)];
    s += (v.x + v.y) + (v.z + v.w);
    ushort4 b;
    b.x = f2b(v.x); b.y = f2b(v.y); b.z = f2b(v.z); b.w = f2b(v.w);
    *(ushort4*)(wr + (size_t)(lane + (i << 6)) * 4) = b;
  }
#pragma unroll
  for (int o = 32; o > 0; o >>= 1) s += __shfl_xor(s, o, 64);
  if (lane == 0) inv_deg[row] = 1.0f / s;
}

// ---------------- k2: dst[c][k] = bf16(src[k][c] * scale[k])  (src is [K][256] f32)
__global__ __launch_bounds__(256) void transpose_scale_kernel(const float* __restrict__ src,
                                                              const float* __restrict__ scale,
                                                              ushort* __restrict__ dst, int K) {
  __shared__ ushort tile[64 * 256];
  const int k0 = blockIdx.x * 64;
  const int w = threadIdx.x >> 6;
  const int lane = threadIdx.x & 63;
#pragma unroll
  for (int i = 0; i < 16; ++i) {
    const int r = w * 16 + i;
    float4 v = *(const float4*)(src + (size_t)(k0 + r) * DDIM + lane * 4);
    const float sc = scale ? scale[k0 + r] : 1.0f;
    ushort4 b;
    b.x = f2b(v.x * sc); b.y = f2b(v.y * sc);
    b.z = f2b(v.z * sc); b.w = f2b(v.w * sc);
    *(ushort4*)&tile[r * 256 + lane * 4] = b;
  }
  __syncthreads();
  const int c = threadIdx.x;  // 0..255: one output row (column of src)
  ushort* drow = dst + (size_t)c * K + k0;
#pragma unroll
  for (int s = 0; s < 8; ++s) {
    uint32_t p[4];
#pragma unroll
    for (int j = 0; j < 4; ++j) {
      uint32_t lo = tile[(s * 8 + 2 * j + 0) * 256 + c];
      uint32_t hi = tile[(s * 8 + 2 * j + 1) * 256 + c];
      p[j] = lo | (hi << 16);
    }
    uint4 u; u.x = p[0]; u.y = p[1]; u.z = p[2]; u.w = p[3];
    *(uint4*)(drow + s * 8) = u;
  }
}

// ---------------- k3: Cpart[ks] = rowscale * (Ab[:, ks*2048:+2048] @ Yt^T) ----------
// BM=128, BN=256 (full N), BK=64, 8 waves (2Mx4N), LDS 96KB double-buffered.
// Both A and B staged via global_load_lds (16B) with XOR swizzle chunk^=(row&7),
// applied as pre-swizzled GLOBAL source + swizzled ds_read (rule #21).
__global__ __launch_bounds__(512, 2) void gemm_big_kernel(
    const ushort* __restrict__ Ab,   // [8192][8192] bf16
    const ushort* __restrict__ Bt,   // [256][8192] bf16 (Yt, k-contiguous)
    const float* __restrict__ rowscale,
    float* __restrict__ Cpart) {     // [4][8192][256] f32
  __shared__ ushort Asm[2][128 * 64];  // 16 KB x2
  __shared__ ushort Bsm[2][256 * 64];  // 32 KB x2

  const int tid = threadIdx.x;
  const int lane = tid & 63;
  const int w = tid >> 6;   // 0..7
  const int wm = w >> 2;    // 0..1
  const int wn = w & 3;     // 0..3

  const int ks = blockIdx.x & 3;   // constant per XCD (blockIdx%8 round-robin)
  const int mb = blockIdx.x >> 2;  // 0..63
  const int m0 = mb * 128;
  const size_t kstart = (size_t)ks * 2048;

  // staging: lane l -> sub-row (l>>3), chunk c'=(l&7); global src chunk = c'^(row&7)
  const int al_r = lane >> 3;          // 0..7 (== row&7 since group bases are mult of 8)
  const int al_c = lane & 7;
  const int asw = al_c ^ al_r;
  const char* agA = (const char*)(Ab + (size_t)(m0 + 16 * w + al_r) * NROWS + kstart) + asw * 16;
  const char* bgB = (const char*)(Bt + (size_t)(32 * w + al_r) * NROWS + kstart) + asw * 16;
  const size_t grp = (size_t)8 * NROWS * 2;  // 8 rows of global stride, bytes

  // fragment read params
  const int fr = lane & 15;
  const int q = lane >> 4;    // 0..3
  const int fsw = fr & 7;     // == row&7 and col&7 of the fragment row

  f32x4 acc[4][4] = {};
  const int NT = 2048 / 64;  // 32

  // prologue: stage tile 0 into buffer 0
  {
    glds16(agA, &Asm[0][(16 * w + 0) * 64]);
    glds16(agA + grp, &Asm[0][(16 * w + 8) * 64]);
#pragma unroll
    for (int j = 0; j < 4; ++j)
      glds16(bgB + (size_t)j * grp, &Bsm[0][(32 * w + 8 * j) * 64]);
  }

  int cur = 0;
  for (int t = 0; t < NT; ++t) {
    __syncthreads();  // drains vmcnt -> tile t resident in buf cur
    if (t + 1 < NT) {
      const size_t koff = (size_t)(t + 1) * 128;  // 64 k * 2 B
      glds16(agA + koff, &Asm[cur ^ 1][(16 * w + 0) * 64]);
      glds16(agA + grp + koff, &Asm[cur ^ 1][(16 * w + 8) * 64]);
#pragma unroll
      for (int j = 0; j < 4; ++j)
        glds16(bgB + (size_t)j * grp + koff, &Bsm[cur ^ 1][(32 * w + 8 * j) * 64]);
    }
#pragma unroll
    for (int kk = 0; kk < 2; ++kk) {
      uint4 af[4], bfr[4];
#pragma unroll
      for (int m = 0; m < 4; ++m)
        af[m] = *(const uint4*)((const char*)&Asm[cur][0] +
                 ((64 * wm + 16 * m + fr) * 128 + (((4 * kk + q) ^ fsw) << 4)));
#pragma unroll
      for (int n = 0; n < 4; ++n)
        bfr[n] = *(const uint4*)((const char*)&Bsm[cur][0] +
                 ((64 * wn + 16 * n + fr) * 128 + (((4 * kk + q) ^ fsw) << 4)));
#pragma unroll
      for (int m = 0; m < 4; ++m)
#pragma unroll
        for (int n = 0; n < 4; ++n)
          acc[m][n] = __builtin_amdgcn_mfma_f32_16x16x32_bf16(
              __builtin_bit_cast(bf16x8, af[m]), __builtin_bit_cast(bf16x8, bfr[n]),
              acc[m][n], 0, 0, 0);
    }
    cur ^= 1;
  }

  // epilogue: D layout col=lane&15, row=(lane>>4)*4+reg  [m89]
  float* Cp = Cpart + (size_t)ks * ((size_t)NROWS * DDIM);
#pragma unroll
  for (int m = 0; m < 4; ++m)
#pragma unroll
    for (int r = 0; r < 4; ++r) {
      const int row = m0 + 64 * wm + 16 * m + q * 4 + r;
      const float sc = rowscale[row];
#pragma unroll
      for (int n = 0; n < 4; ++n) {
        const int col = 64 * wn + 16 * n + fr;
        Cp[(size_t)row * DDIM + col] = acc[m][n][r] * sc;
      }
    }
}

// ---------------- k4: out = relu((sum_p Hp[p]) @ Wt^T + bias) ----------------
// BM=32, BN=256, BK=32, 8 waves; B via glds16 (swizzled), A reg-staged f32->bf16.
__global__ __launch_bounds__(512, 4) void gemm_small_kernel(
    const float* __restrict__ Hp, int npart, size_t pstride,
    const ushort* __restrict__ Bt,  // [256][256] bf16
    const float* __restrict__ bias, float* __restrict__ C) {
  const int K = DDIM;
  __shared__ ushort Asm[2][32 * 32];
  __shared__ ushort Bsm[2][256 * 32];

  const int tid = threadIdx.x;
  const int lane = tid & 63;
  const int w = tid >> 6;
  const int m0 = blockIdx.x * 32;

  f32x4 acc[2][2] = {};
  const int NT = K >> 5;  // 8

  const int arow = tid >> 3;
  const int aseg = tid & 7;
  const float* ag = Hp + (size_t)(m0 + arow) * DDIM + aseg * 4;
  const int awoff = arow * 32 + ((((aseg >> 1) ^ ((arow >> 1) & 3)) << 3) | ((aseg & 1) << 2));

  const int bch0 = w * 2;
  const int bq = lane >> 2;
  const int bswz = (lane & 3) ^ ((lane >> 3) & 3);
  const char* bg0 = (const char*)Bt + (size_t)(bch0 * 16 + bq) * ((size_t)K * 2) + bswz * 16;
  const char* bg1 = bg0 + (size_t)16 * ((size_t)K * 2);

  const int fr = lane & 15;
  const int fsw = (fr >> 1) & 3;
  const int fch = (lane >> 4) ^ fsw;
  const int aoff0 = fr * 32 + (fch << 3);
  const int aoff1 = (16 + fr) * 32 + (fch << 3);
  const int boff0 = (w * 32 + fr) * 32 + (fch << 3);
  const int boff1 = (w * 32 + 16 + fr) * 32 + (fch << 3);

  auto loadA = [&](int t) {
    float4 v; v.x = v.y = v.z = v.w = 0.f;
    for (int p = 0; p < npart; ++p) {
      float4 u = *(const float4*)(ag + (size_t)p * pstride + t * 32);
      v.x += u.x; v.y += u.y; v.z += u.z; v.w += u.w;
    }
    return v;
  };

  if (tid < 256) {
    float4 v = loadA(0);
    ushort4 b; b.x = f2b(v.x); b.y = f2b(v.y); b.z = f2b(v.z); b.w = f2b(v.w);
    *(ushort4*)&Asm[0][awoff] = b;
  }
  glds16(bg0, &Bsm[0][(bch0 + 0) * 512]);
  glds16(bg1, &Bsm[0][(bch0 + 1) * 512]);

  int cur = 0;
  for (int t = 0; t < NT; ++t) {
    __syncthreads();
    const bool pf = (t + 1 < NT);
    float4 av;
    if (pf) {
      if (tid < 256) av = loadA(t + 1);
      glds16(bg0 + (size_t)(t + 1) * 64, &Bsm[cur ^ 1][(bch0 + 0) * 512]);
      glds16(bg1 + (size_t)(t + 1) * 64, &Bsm[cur ^ 1][(bch0 + 1) * 512]);
    }
    uint4 a0 = *(const uint4*)&Asm[cur][aoff0];
    uint4 a1 = *(const uint4*)&Asm[cur][aoff1];
    uint4 b0 = *(const uint4*)&Bsm[cur][boff0];
    uint4 b1 = *(const uint4*)&Bsm[cur][boff1];
    acc[0][0] = __builtin_amdgcn_mfma_f32_16x16x32_bf16(
        __builtin_bit_cast(bf16x8, a0), __builtin_bit_cast(bf16x8, b0), acc[0][0], 0, 0, 0);
    acc[0][1] = __builtin_amdgcn_mfma_f32_16x16x32_bf16(
        __builtin_bit_cast(bf16x8, a0), __builtin_bit_cast(bf16x8, b1), acc[0][1], 0, 0, 0);
    acc[1][0] = __builtin_amdgcn_mfma_f32_16x16x32_bf16(
        __builtin_bit_cast(bf16x8, a1), __builtin_bit_cast(bf16x8, b0), acc[1][0], 0, 0, 0);
    acc[1][1] = __builtin_amdgcn_mfma_f32_16x16x32_bf16(
        __builtin_bit_cast(bf16x8, a1), __builtin_bit_cast(bf16x8, b1), acc[1][1], 0, 0, 0);
    if (pf && tid < 256) {
      ushort4 b; b.x = f2b(av.x); b.y = f2b(av.y); b.z = f2b(av.z); b.w = f2b(av.w);
      *(ushort4*)&Asm[cur ^ 1][awoff] = b;
    }
    cur ^= 1;
  }

#pragma unroll
  for (int m = 0; m < 2; ++m)
#pragma unroll
    for (int n = 0; n < 2; ++n) {
      const int col = w * 32 + n * 16 + fr;
      const float bv = bias[col];
#pragma unroll
      for (int r = 0; r < 4; ++r) {
        const int row = m0 + m * 16 + (lane >> 4) * 4 + r;
        float x = acc[m][n][r] + bv;
        x = fmaxf(x, 0.f);
        C[(size_t)row * DDIM + col] = x;
      }
    }
}

extern "C" void kernel_launch(void* const* d_in, const int* in_sizes, int n_in,
                              void* d_out, int out_size, void* d_ws, size_t ws_size,
                              hipStream_t stream) {
  const float* x      = (const float*)d_in[0];
  const float* adj    = (const float*)d_in[1];
  const float* weight = (const float*)d_in[2];
  const float* bias   = (const float*)d_in[3];
  float* out = (float*)d_out;

  char* ws = (char*)d_ws;
  const size_t ab_bytes = (size_t)NROWS * NROWS * 2;     // 128 MB bf16 A
  const size_t h_bytes  = 4ull * NROWS * DDIM * 4;       // 32 MB: 4 k-split partials
  const size_t yt_bytes = (size_t)DDIM * NROWS * 2;      // 4 MB
  const size_t wt_bytes = (size_t)DDIM * DDIM * 2;       // 128 KB
  ushort* Ab      = (ushort*)ws;
  float*  hpart   = (float*)(ws + ab_bytes);
  ushort* Yt      = (ushort*)(ws + ab_bytes + h_bytes);
  ushort* Wt      = (ushort*)(ws + ab_bytes + h_bytes + yt_bytes);
  float*  inv_deg = (float*)(ws + ab_bytes + h_bytes + yt_bytes + wt_bytes);
  const size_t need = ab_bytes + h_bytes + yt_bytes + wt_bytes + (size_t)NROWS * 4;
  if (ws_size < need) { fprintf(stderr, "ws too small: %zu < %zu\n", ws_size, need); return; }

  // k1: degrees + bf16 cast of A
  degree_cast_kernel<<<NROWS / 4, 256, 0, stream>>>(adj, Ab, inv_deg);
  // k2a: Yt[c][k] = bf16(x[k][c] * inv_deg[k]);  k2b: Wt[n][d] = bf16(W[d][n])
  transpose_scale_kernel<<<NROWS / 64, 256, 0, stream>>>(x, inv_deg, Yt, NROWS);
  transpose_scale_kernel<<<DDIM / 64, 256, 0, stream>>>(weight, nullptr, Wt, DDIM);
  // k3: hpart[ks] = inv_deg * (Ab @ Yt^T) over k-quarter ks (256 blocks, 1/CU)
  gemm_big_kernel<<<dim3(256), 512, 0, stream>>>(Ab, Yt, inv_deg, hpart);
  // k4: out = relu((sum of 4 partials) @ Wt^T + bias)
  gemm_small_kernel<<<dim3(256), 512, 0, stream>>>(hpart, 4, (size_t)NROWS * DDIM, Wt, bias, out);
}

// Round 3
// 463.751 us; speedup vs baseline: 1.1009x; 1.0180x over previous
//
#include <hip/hip_runtime.h>
#include <stdint.h>
#include <stdio.h>

#define NROWS 8192
#define DDIM 256

typedef __attribute__((ext_vector_type(8))) __bf16 bf16x8;
typedef __attribute__((ext_vector_type(4))) float f32x4;
typedef __attribute__((address_space(3))) uint32_t as3u32;
typedef __attribute__((address_space(1))) uint32_t as1u32;

__device__ __forceinline__ void glds16(const void* g, void* l) {
  __builtin_amdgcn_global_load_lds((const as1u32*)g, (as3u32*)l, 16, 0, 0);
}

// round-to-nearest-even f32 -> bf16 bits
__device__ __forceinline__ ushort f2b(float f) {
  uint32_t u = __float_as_uint(f);
  return (ushort)((u + 0x7FFFu + ((u >> 16) & 1u)) >> 16);
}

// ---------------- k1: inv_deg[i] = 1/sum_k A[i,k]; Ab = bf16(A) ----------------
__global__ __launch_bounds__(256) void degree_cast_kernel(const float* __restrict__ A,
                                                          ushort* __restrict__ Ab,
                                                          float* __restrict__ inv_deg) {
  const int row = blockIdx.x * 4 + (threadIdx.x >> 6);
  const int lane = threadIdx.x & 63;
  const float4* r4 = (const float4*)(A + (size_t)row * NROWS);
  ushort* wr = Ab + (size_t)row * NROWS;
  float s = 0.f;
#pragma unroll
  for (int i = 0; i < 32; ++i) {
    float4 v = r4[lane + (i << 6)];
    s += (v.x + v.y) + (v.z + v.w);
    ushort4 b;
    b.x = f2b(v.x); b.y = f2b(v.y); b.z = f2b(v.z); b.w = f2b(v.w);
    *(ushort4*)(wr + (size_t)(lane + (i << 6)) * 4) = b;
  }
#pragma unroll
  for (int o = 32; o > 0; o >>= 1) s += __shfl_xor(s, o, 64);
  if (lane == 0) inv_deg[row] = 1.0f / s;
}

// ---------------- k2: dst[c][k] = bf16(src[k][c] * scale[k])  (src is [K][256] f32)
__global__ __launch_bounds__(256) void transpose_scale_kernel(const float* __restrict__ src,
                                                              const float* __restrict__ scale,
                                                              ushort* __restrict__ dst, int K) {
  __shared__ ushort tile[64 * 256];
  const int k0 = blockIdx.x * 64;
  const int w = threadIdx.x >> 6;
  const int lane = threadIdx.x & 63;
#pragma unroll
  for (int i = 0; i < 16; ++i) {
    const int r = w * 16 + i;
    float4 v = *(const float4*)(src + (size_t)(k0 + r) * DDIM + lane * 4);
    const float sc = scale ? scale[k0 + r] : 1.0f;
    ushort4 b;
    b.x = f2b(v.x * sc); b.y = f2b(v.y * sc);
    b.z = f2b(v.z * sc); b.w = f2b(v.w * sc);
    *(ushort4*)&tile[r * 256 + lane * 4] = b;
  }
  __syncthreads();
  const int c = threadIdx.x;  // 0..255: one output row (column of src)
  ushort* drow = dst + (size_t)c * K + k0;
#pragma unroll
  for (int s = 0; s < 8; ++s) {
    uint32_t p[4];
#pragma unroll
    for (int j = 0; j < 4; ++j) {
      uint32_t lo = tile[(s * 8 + 2 * j + 0) * 256 + c];
      uint32_t hi = tile[(s * 8 + 2 * j + 1) * 256 + c];
      p[j] = lo | (hi << 16);
    }
    uint4 u; u.x = p[0]; u.y = p[1]; u.z = p[2]; u.w = p[3];
    *(uint4*)(drow + s * 8) = u;
  }
}

// ---------------- k3: Cpart[ks] = rowscale * (Ab[:, ks*2048:+2048] @ Yt^T) ----------
// 256 threads (4 waves), BM=64, BN=256 (full N -> A read once), BK=64.
// Wave-tile 64x64 (4x4 fragments) for minimal ds_read/MFMA ratio.
// LDS 80 KB double-buffered -> 2 blocks/CU resident (barrier-stall overlap across blocks).
// A and B staged via global_load_lds (16B) with XOR swizzle chunk^=(row&7),
// pre-swizzled GLOBAL source + swizzled ds_read (rule #21).
__global__ __launch_bounds__(256, 2) void gemm_big_kernel(
    const ushort* __restrict__ Ab,   // [8192][8192] bf16
    const ushort* __restrict__ Bt,   // [256][8192] bf16 (Yt, k-contiguous)
    const float* __restrict__ rowscale,
    float* __restrict__ Cpart) {     // [4][8192][256] f32
  __shared__ ushort Asm[2][64 * 64];   // 8 KB x2
  __shared__ ushort Bsm[2][256 * 64];  // 32 KB x2

  const int tid = threadIdx.x;
  const int lane = tid & 63;
  const int w = tid >> 6;   // 0..3; wave w owns output cols 64w..64w+63

  const int ks = blockIdx.x & 3;   // one ks pair per XCD -> 1 MB B-slice L2-resident
  const int mb = blockIdx.x >> 2;  // 0..127
  const int m0 = mb * 64;
  const size_t kstart = (size_t)ks * 2048;

  // staging: lane l -> sub-row (l>>3), chunk c'=(l&7); global chunk = c'^(row&7)
  const int al_r = lane >> 3;
  const int al_c = lane & 7;
  const int asw = al_c ^ al_r;
  const char* agA = (const char*)(Ab + (size_t)(m0 + 16 * w + al_r) * NROWS + kstart) + asw * 16;
  const char* bgB = (const char*)(Bt + (size_t)(64 * w + al_r) * NROWS + kstart) + asw * 16;
  const size_t grp = (size_t)8 * NROWS * 2;  // 8 global rows, bytes

  // fragment read params
  const int fr = lane & 15;
  const int q = lane >> 4;   // 0..3
  const int fsw = fr & 7;    // == row&7 for rows = 16m+fr / 16n+fr (bases mult of 8... of 16)

  f32x4 acc[4][4] = {};
  const int NT = 2048 / 64;  // 32

  auto stage = [&](int buf, int t) {
    const size_t koff = (size_t)t * 128;  // 64 k * 2 B
    glds16(agA + koff, &Asm[buf][(16 * w + 0) * 64]);
    glds16(agA + grp + koff, &Asm[buf][(16 * w + 8) * 64]);
#pragma unroll
    for (int j = 0; j < 8; ++j)
      glds16(bgB + (size_t)j * grp + koff, &Bsm[buf][(64 * w + 8 * j) * 64]);
  };

  stage(0, 0);
  int cur = 0;
  for (int t = 0; t < NT; ++t) {
    __syncthreads();  // drains vmcnt -> tile t resident in buf cur
    if (t + 1 < NT) stage(cur ^ 1, t + 1);
#pragma unroll
    for (int kk = 0; kk < 2; ++kk) {
      uint4 af[4], bfr[4];
#pragma unroll
      for (int m = 0; m < 4; ++m)
        af[m] = *(const uint4*)((const char*)&Asm[cur][0] +
                 ((16 * m + fr) * 128 + (((4 * kk + q) ^ fsw) << 4)));
#pragma unroll
      for (int n = 0; n < 4; ++n)
        bfr[n] = *(const uint4*)((const char*)&Bsm[cur][0] +
                 ((64 * w + 16 * n + fr) * 128 + (((4 * kk + q) ^ fsw) << 4)));
#pragma unroll
      for (int m = 0; m < 4; ++m)
#pragma unroll
        for (int n = 0; n < 4; ++n)
          acc[m][n] = __builtin_amdgcn_mfma_f32_16x16x32_bf16(
              __builtin_bit_cast(bf16x8, af[m]), __builtin_bit_cast(bf16x8, bfr[n]),
              acc[m][n], 0, 0, 0);
    }
    cur ^= 1;
  }

  // epilogue: D layout col=lane&15, row=(lane>>4)*4+reg  [m89]
  float* Cp = Cpart + (size_t)ks * ((size_t)NROWS * DDIM);
#pragma unroll
  for (int m = 0; m < 4; ++m)
#pragma unroll
    for (int r = 0; r < 4; ++r) {
      const int row = m0 + 16 * m + q * 4 + r;
      const float sc = rowscale[row];
#pragma unroll
      for (int n = 0; n < 4; ++n) {
        const int col = 64 * w + 16 * n + fr;
        Cp[(size_t)row * DDIM + col] = acc[m][n][r] * sc;
      }
    }
}

// ---------------- k4: out = relu((sum of 4 partials) @ Wt^T + bias) ----------------
// BM=32, BN=256, BK=32, 8 waves; B via glds16 (swizzled), A reg-staged f32->bf16.
__global__ __launch_bounds__(512, 4) void gemm_small_kernel(
    const float* __restrict__ Hp,   // [4][8192][256] f32 partials
    const ushort* __restrict__ Bt,  // [256][256] bf16
    const float* __restrict__ bias, float* __restrict__ C) {
  const int K = DDIM;
  const size_t PS = (size_t)NROWS * DDIM;
  __shared__ ushort Asm[2][32 * 32];
  __shared__ ushort Bsm[2][256 * 32];

  const int tid = threadIdx.x;
  const int lane = tid & 63;
  const int w = tid >> 6;
  const int m0 = blockIdx.x * 32;

  f32x4 acc[2][2] = {};
  const int NT = K >> 5;  // 8

  const int arow = tid >> 3;
  const int aseg = tid & 7;
  const float* ag = Hp + (size_t)(m0 + arow) * DDIM + aseg * 4;
  const int awoff = arow * 32 + ((((aseg >> 1) ^ ((arow >> 1) & 3)) << 3) | ((aseg & 1) << 2));

  const int bch0 = w * 2;
  const int bq = lane >> 2;
  const int bswz = (lane & 3) ^ ((lane >> 3) & 3);
  const char* bg0 = (const char*)Bt + (size_t)(bch0 * 16 + bq) * ((size_t)K * 2) + bswz * 16;
  const char* bg1 = bg0 + (size_t)16 * ((size_t)K * 2);

  const int fr = lane & 15;
  const int fsw = (fr >> 1) & 3;
  const int fch = (lane >> 4) ^ fsw;
  const int aoff0 = fr * 32 + (fch << 3);
  const int aoff1 = (16 + fr) * 32 + (fch << 3);
  const int boff0 = (w * 32 + fr) * 32 + (fch << 3);
  const int boff1 = (w * 32 + 16 + fr) * 32 + (fch << 3);

  auto loadA = [&](int t) {
    float4 u0 = *(const float4*)(ag + 0 * PS + t * 32);
    float4 u1 = *(const float4*)(ag + 1 * PS + t * 32);
    float4 u2 = *(const float4*)(ag + 2 * PS + t * 32);
    float4 u3 = *(const float4*)(ag + 3 * PS + t * 32);
    float4 v;
    v.x = (u0.x + u1.x) + (u2.x + u3.x);
    v.y = (u0.y + u1.y) + (u2.y + u3.y);
    v.z = (u0.z + u1.z) + (u2.z + u3.z);
    v.w = (u0.w + u1.w) + (u2.w + u3.w);
    return v;
  };

  if (tid < 256) {
    float4 v = loadA(0);
    ushort4 b; b.x = f2b(v.x); b.y = f2b(v.y); b.z = f2b(v.z); b.w = f2b(v.w);
    *(ushort4*)&Asm[0][awoff] = b;
  }
  glds16(bg0, &Bsm[0][(bch0 + 0) * 512]);
  glds16(bg1, &Bsm[0][(bch0 + 1) * 512]);

  int cur = 0;
  for (int t = 0; t < NT; ++t) {
    __syncthreads();
    const bool pf = (t + 1 < NT);
    float4 av;
    if (pf) {
      if (tid < 256) av = loadA(t + 1);
      glds16(bg0 + (size_t)(t + 1) * 64, &Bsm[cur ^ 1][(bch0 + 0) * 512]);
      glds16(bg1 + (size_t)(t + 1) * 64, &Bsm[cur ^ 1][(bch0 + 1) * 512]);
    }
    uint4 a0 = *(const uint4*)&Asm[cur][aoff0];
    uint4 a1 = *(const uint4*)&Asm[cur][aoff1];
    uint4 b0 = *(const uint4*)&Bsm[cur][boff0];
    uint4 b1 = *(const uint4*)&Bsm[cur][boff1];
    acc[0][0] = __builtin_amdgcn_mfma_f32_16x16x32_bf16(
        __builtin_bit_cast(bf16x8, a0), __builtin_bit_cast(bf16x8, b0), acc[0][0], 0, 0, 0);
    acc[0][1] = __builtin_amdgcn_mfma_f32_16x16x32_bf16(
        __builtin_bit_cast(bf16x8, a0), __builtin_bit_cast(bf16x8, b1), acc[0][1], 0, 0, 0);
    acc[1][0] = __builtin_amdgcn_mfma_f32_16x16x32_bf16(
        __builtin_bit_cast(bf16x8, a1), __builtin_bit_cast(bf16x8, b0), acc[1][0], 0, 0, 0);
    acc[1][1] = __builtin_amdgcn_mfma_f32_16x16x32_bf16(
        __builtin_bit_cast(bf16x8, a1), __builtin_bit_cast(bf16x8, b1), acc[1][1], 0, 0, 0);
    if (pf && tid < 256) {
      ushort4 b; b.x = f2b(av.x); b.y = f2b(av.y); b.z = f2b(av.z); b.w = f2b(av.w);
      *(ushort4*)&Asm[cur ^ 1][awoff] = b;
    }
    cur ^= 1;
  }

#pragma unroll
  for (int m = 0; m < 2; ++m)
#pragma unroll
    for (int n = 0; n < 2; ++n) {
      const int col = w * 32 + n * 16 + fr;
      const float bv = bias[col];
#pragma unroll
      for (int r = 0; r < 4; ++r) {
        const int row = m0 + m * 16 + (lane >> 4) * 4 + r;
        float x = acc[m][n][r] + bv;
        x = fmaxf(x, 0.f);
        C[(size_t)row * DDIM + col] = x;
      }
    }
}

extern "C" void kernel_launch(void* const* d_in, const int* in_sizes, int n_in,
                              void* d_out, int out_size, void* d_ws, size_t ws_size,
                              hipStream_t stream) {
  const float* x      = (const float*)d_in[0];
  const float* adj    = (const float*)d_in[1];
  const float* weight = (const float*)d_in[2];
  const float* bias   = (const float*)d_in[3];
  float* out = (float*)d_out;

  char* ws = (char*)d_ws;
  const size_t ab_bytes = (size_t)NROWS * NROWS * 2;     // 128 MB bf16 A
  const size_t h_bytes  = 4ull * NROWS * DDIM * 4;       // 32 MB: 4 k-split partials
  const size_t yt_bytes = (size_t)DDIM * NROWS * 2;      // 4 MB
  const size_t wt_bytes = (size_t)DDIM * DDIM * 2;       // 128 KB
  ushort* Ab      = (ushort*)ws;
  float*  hpart   = (float*)(ws + ab_bytes);
  ushort* Yt      = (ushort*)(ws + ab_bytes + h_bytes);
  ushort* Wt      = (ushort*)(ws + ab_bytes + h_bytes + yt_bytes);
  float*  inv_deg = (float*)(ws + ab_bytes + h_bytes + yt_bytes + wt_bytes);
  const size_t need = ab_bytes + h_bytes + yt_bytes + wt_bytes + (size_t)NROWS * 4;
  if (ws_size < need) { fprintf(stderr, "ws too small: %zu < %zu\n", ws_size, need); return; }

  // k1: degrees + bf16 cast of A
  degree_cast_kernel<<<NROWS / 4, 256, 0, stream>>>(adj, Ab, inv_deg);
  // k2a: Yt[c][k] = bf16(x[k][c] * inv_deg[k]);  k2b: Wt[n][d] = bf16(W[d][n])
  transpose_scale_kernel<<<NROWS / 64, 256, 0, stream>>>(x, inv_deg, Yt, NROWS);
  transpose_scale_kernel<<<DDIM / 64, 256, 0, stream>>>(weight, nullptr, Wt, DDIM);
  // k3: hpart[ks] = inv_deg * (Ab @ Yt^T) over k-quarter ks (512 blocks = 2/CU resident)
  gemm_big_kernel<<<dim3(512), 256, 0, stream>>>(Ab, Yt, inv_deg, hpart);
  // k4: out = relu((sum of 4 partials) @ Wt^T + bias)
  gemm_small_kernel<<<dim3(256), 512, 0, stream>>>(hpart, Wt, bias, out);
}

// Round 6
// 417.869 us; speedup vs baseline: 1.2217x; 1.1098x over previous
//
#include <hip/hip_runtime.h>
#include <stdint.h>
#include <stdio.h>

#define NROWS 8192
#define DDIM 256

typedef __attribute__((ext_vector_type(8))) __bf16 bf16x8;
typedef __attribute__((ext_vector_type(4))) float f32x4;
typedef __attribute__((address_space(3))) uint32_t as3u32;
typedef __attribute__((address_space(1))) uint32_t as1u32;

__device__ __forceinline__ void glds16(const void* g, void* l) {
  __builtin_amdgcn_global_load_lds((const as1u32*)g, (as3u32*)l, 16, 0, 0);
}

// round-to-nearest-even f32 -> bf16 bits
__device__ __forceinline__ ushort f2b(float f) {
  uint32_t u = __float_as_uint(f);
  return (ushort)((u + 0x7FFFu + ((u >> 16) & 1u)) >> 16);
}

// ---------------- k1: inv_deg[i] = 1/sum_k A[i,k]; Ab = bf16(A) ----------------
// Nontemporal loads of the f32 A stream: A is never re-read as f32, and keeping it
// out of L3 preserves the 128 MiB Ab write-allocate for k3's re-read (L3-hit).
__global__ __launch_bounds__(256) void degree_cast_kernel(const float* __restrict__ A,
                                                          ushort* __restrict__ Ab,
                                                          float* __restrict__ inv_deg) {
  const int row = blockIdx.x * 4 + (threadIdx.x >> 6);
  const int lane = threadIdx.x & 63;
  const f32x4* r4 = (const f32x4*)(A + (size_t)row * NROWS);
  ushort* wr = Ab + (size_t)row * NROWS;
  float s = 0.f;
#pragma unroll
  for (int i = 0; i < 32; ++i) {
    f32x4 v = __builtin_nontemporal_load(r4 + lane + (i << 6));
    s += (v[0] + v[1]) + (v[2] + v[3]);
    ushort4 b;
    b.x = f2b(v[0]); b.y = f2b(v[1]); b.z = f2b(v[2]); b.w = f2b(v[3]);
    *(ushort4*)(wr + (size_t)(lane + (i << 6)) * 4) = b;
  }
#pragma unroll
  for (int o = 32; o > 0; o >>= 1) s += __shfl_xor(s, o, 64);
  if (lane == 0) inv_deg[row] = 1.0f / s;
}

// ---------------- k2 (merged): transpose+scale x -> Yt  and  transpose W -> Wt
// blocks 0..127: Yt[c][k] = bf16(x[k][c] * inv_deg[k]), K=8192
// blocks 128..131: Wt[n][d] = bf16(W[d][n]), K=256
__global__ __launch_bounds__(256) void transpose_scale_kernel(const float* __restrict__ x,
                                                              const float* __restrict__ W,
                                                              const float* __restrict__ inv_deg,
                                                              ushort* __restrict__ Yt,
                                                              ushort* __restrict__ Wt) {
  __shared__ ushort tile[64 * 256];
  const int bid = blockIdx.x;
  const float* src; ushort* dst; int K; const float* scale; int k0;
  if (bid < 128) { src = x; dst = Yt; K = NROWS; scale = inv_deg; k0 = bid * 64; }
  else           { src = W; dst = Wt; K = DDIM;  scale = nullptr; k0 = (bid - 128) * 64; }

  const int w = threadIdx.x >> 6;
  const int lane = threadIdx.x & 63;
#pragma unroll
  for (int i = 0; i < 16; ++i) {
    const int r = w * 16 + i;
    float4 v = *(const float4*)(src + (size_t)(k0 + r) * DDIM + lane * 4);
    const float sc = scale ? scale[k0 + r] : 1.0f;
    ushort4 b;
    b.x = f2b(v.x * sc); b.y = f2b(v.y * sc);
    b.z = f2b(v.z * sc); b.w = f2b(v.w * sc);
    *(ushort4*)&tile[r * 256 + lane * 4] = b;
  }
  __syncthreads();
  const int c = threadIdx.x;  // 0..255: one output row (column of src)
  ushort* drow = dst + (size_t)c * K + k0;
#pragma unroll
  for (int s = 0; s < 8; ++s) {
    uint32_t p[4];
#pragma unroll
    for (int j = 0; j < 4; ++j) {
      uint32_t lo = tile[(s * 8 + 2 * j + 0) * 256 + c];
      uint32_t hi = tile[(s * 8 + 2 * j + 1) * 256 + c];
      p[j] = lo | (hi << 16);
    }
    uint4 u; u.x = p[0]; u.y = p[1]; u.z = p[2]; u.w = p[3];
    *(uint4*)(drow + s * 8) = u;
  }
}

// ---------------- k3: Cpart[ks] = rowscale * (Ab[:, ks*2048:+2048] @ Yt^T) ----------
// 256 threads (4 waves), BM=64, BN=256, BK=64, wave-tile 64x64 (4x4 frags).
// Depth-2 counted-vmcnt pipeline (T4): tiles t and t+1 always in flight; per iter
//   vmcnt(10) [tile t resident] -> barrier -> ds_read 16 frags -> lgkmcnt(0) ->
//   barrier -> stage tile t+2 into the just-read buffer -> MFMA from regs.
// XOR swizzle chunk^=(row&7): pre-swizzled GLOBAL source + swizzled ds_read (rule #21).
__global__ __launch_bounds__(256, 2) void gemm_big_kernel(
    const ushort* __restrict__ Ab,   // [8192][8192] bf16
    const ushort* __restrict__ Bt,   // [256][8192] bf16 (Yt, k-contiguous)
    const float* __restrict__ rowscale,
    float* __restrict__ Cpart) {     // [4][8192][256] f32
  __shared__ ushort Asm[2][64 * 64];   // 8 KB x2
  __shared__ ushort Bsm[2][256 * 64];  // 32 KB x2

  const int tid = threadIdx.x;
  const int lane = tid & 63;
  const int w = tid >> 6;   // 0..3; wave w owns output cols 64w..64w+63

  const int ks = blockIdx.x & 3;   // constant per XCD -> 1 MB B-slice L2-resident
  const int mb = blockIdx.x >> 2;  // 0..127
  const int m0 = mb * 64;
  const size_t kstart = (size_t)ks * 2048;

  // staging: lane l -> sub-row (l>>3), chunk c'=(l&7); global chunk = c'^(row&7)
  const int al_r = lane >> 3;
  const int al_c = lane & 7;
  const int asw = al_c ^ al_r;
  const char* agA = (const char*)(Ab + (size_t)(m0 + 16 * w + al_r) * NROWS + kstart) + asw * 16;
  const char* bgB = (const char*)(Bt + (size_t)(64 * w + al_r) * NROWS + kstart) + asw * 16;
  const size_t grp = (size_t)8 * NROWS * 2;  // 8 global rows, bytes

  // fragment read params
  const int fr = lane & 15;
  const int q = lane >> 4;   // 0..3
  const int fsw = fr & 7;

  f32x4 acc[4][4] = {};
  const int NT = 2048 / 64;  // 32

  auto stage = [&](int buf, int t) {
    const size_t koff = (size_t)t * 128;  // 64 k * 2 B
    glds16(agA + koff, &Asm[buf][(16 * w + 0) * 64]);
    glds16(agA + grp + koff, &Asm[buf][(16 * w + 8) * 64]);
#pragma unroll
    for (int j = 0; j < 8; ++j)
      glds16(bgB + (size_t)j * grp + koff, &Bsm[buf][(64 * w + 8 * j) * 64]);
  };

  stage(0, 0);
  stage(1, 1);

  int cur = 0;
  for (int t = 0; t < NT; ++t) {
    // tile t resident after waiting for its 10 loads; keep t+1's 10 in flight
    if (t + 1 < NT) { asm volatile("s_waitcnt vmcnt(10)" ::: "memory"); }
    else            { asm volatile("s_waitcnt vmcnt(0)" ::: "memory"); }
    __builtin_amdgcn_s_barrier();

    uint4 af[2][4], bfr[2][4];
#pragma unroll
    for (int kk = 0; kk < 2; ++kk) {
#pragma unroll
      for (int m = 0; m < 4; ++m)
        af[kk][m] = *(const uint4*)((const char*)&Asm[cur][0] +
                     ((16 * m + fr) * 128 + (((4 * kk + q) ^ fsw) << 4)));
#pragma unroll
      for (int n = 0; n < 4; ++n)
        bfr[kk][n] = *(const uint4*)((const char*)&Bsm[cur][0] +
                      ((64 * w + 16 * n + fr) * 128 + (((4 * kk + q) ^ fsw) << 4)));
    }
    // all waves done reading buf cur before it is overwritten by tile t+2
    asm volatile("s_waitcnt lgkmcnt(0)" ::: "memory");
    __builtin_amdgcn_s_barrier();
    if (t + 2 < NT) stage(cur, t + 2);

#pragma unroll
    for (int kk = 0; kk < 2; ++kk)
#pragma unroll
      for (int m = 0; m < 4; ++m)
#pragma unroll
        for (int n = 0; n < 4; ++n)
          acc[m][n] = __builtin_amdgcn_mfma_f32_16x16x32_bf16(
              __builtin_bit_cast(bf16x8, af[kk][m]), __builtin_bit_cast(bf16x8, bfr[kk][n]),
              acc[m][n], 0, 0, 0);
    cur ^= 1;
  }

  // epilogue: D layout col=lane&15, row=(lane>>4)*4+reg  [m89]
  float* Cp = Cpart + (size_t)ks * ((size_t)NROWS * DDIM);
#pragma unroll
  for (int m = 0; m < 4; ++m)
#pragma unroll
    for (int r = 0; r < 4; ++r) {
      const int row = m0 + 16 * m + q * 4 + r;
      const float sc = rowscale[row];
#pragma unroll
      for (int n = 0; n < 4; ++n) {
        const int col = 64 * w + 16 * n + fr;
        Cp[(size_t)row * DDIM + col] = acc[m][n][r] * sc;
      }
    }
}

// ---------------- k4: out = relu((sum of 4 partials) @ Wt^T + bias) ----------------
// BM=32, BN=256, BK=32, 8 waves; B via glds16 (swizzled), A reg-staged f32->bf16.
__global__ __launch_bounds__(512, 4) void gemm_small_kernel(
    const float* __restrict__ Hp,   // [4][8192][256] f32 partials
    const ushort* __restrict__ Bt,  // [256][256] bf16
    const float* __restrict__ bias, float* __restrict__ C) {
  const int K = DDIM;
  const size_t PS = (size_t)NROWS * DDIM;
  __shared__ ushort Asm[2][32 * 32];
  __shared__ ushort Bsm[2][256 * 32];

  const int tid = threadIdx.x;
  const int lane = tid & 63;
  const int w = tid >> 6;
  const int m0 = blockIdx.x * 32;

  f32x4 acc[2][2] = {};
  const int NT = K >> 5;  // 8

  const int arow = tid >> 3;
  const int aseg = tid & 7;
  const float* ag = Hp + (size_t)(m0 + arow) * DDIM + aseg * 4;
  const int awoff = arow * 32 + ((((aseg >> 1) ^ ((arow >> 1) & 3)) << 3) | ((aseg & 1) << 2));

  const int bch0 = w * 2;
  const int bq = lane >> 2;
  const int bswz = (lane & 3) ^ ((lane >> 3) & 3);
  const char* bg0 = (const char*)Bt + (size_t)(bch0 * 16 + bq) * ((size_t)K * 2) + bswz * 16;
  const char* bg1 = bg0 + (size_t)16 * ((size_t)K * 2);

  const int fr = lane & 15;
  const int fsw = (fr >> 1) & 3;
  const int fch = (lane >> 4) ^ fsw;
  const int aoff0 = fr * 32 + (fch << 3);
  const int aoff1 = (16 + fr) * 32 + (fch << 3);
  const int boff0 = (w * 32 + fr) * 32 + (fch << 3);
  const int boff1 = (w * 32 + 16 + fr) * 32 + (fch << 3);

  auto loadA = [&](int t) {
    float4 u0 = *(const float4*)(ag + 0 * PS + t * 32);
    float4 u1 = *(const float4*)(ag + 1 * PS + t * 32);
    float4 u2 = *(const float4*)(ag + 2 * PS + t * 32);
    float4 u3 = *(const float4*)(ag + 3 * PS + t * 32);
    float4 v;
    v.x = (u0.x + u1.x) + (u2.x + u3.x);
    v.y = (u0.y + u1.y) + (u2.y + u3.y);
    v.z = (u0.z + u1.z) + (u2.z + u3.z);
    v.w = (u0.w + u1.w) + (u2.w + u3.w);
    return v;
  };

  if (tid < 256) {
    float4 v = loadA(0);
    ushort4 b; b.x = f2b(v.x); b.y = f2b(v.y); b.z = f2b(v.z); b.w = f2b(v.w);
    *(ushort4*)&Asm[0][awoff] = b;
  }
  glds16(bg0, &Bsm[0][(bch0 + 0) * 512]);
  glds16(bg1, &Bsm[0][(bch0 + 1) * 512]);

  int cur = 0;
  for (int t = 0; t < NT; ++t) {
    __syncthreads();
    const bool pf = (t + 1 < NT);
    float4 av;
    if (pf) {
      if (tid < 256) av = loadA(t + 1);
      glds16(bg0 + (size_t)(t + 1) * 64, &Bsm[cur ^ 1][(bch0 + 0) * 512]);
      glds16(bg1 + (size_t)(t + 1) * 64, &Bsm[cur ^ 1][(bch0 + 1) * 512]);
    }
    uint4 a0 = *(const uint4*)&Asm[cur][aoff0];
    uint4 a1 = *(const uint4*)&Asm[cur][aoff1];
    uint4 b0 = *(const uint4*)&Bsm[cur][boff0];
    uint4 b1 = *(const uint4*)&Bsm[cur][boff1];
    acc[0][0] = __builtin_amdgcn_mfma_f32_16x16x32_bf16(
        __builtin_bit_cast(bf16x8, a0), __builtin_bit_cast(bf16x8, b0), acc[0][0], 0, 0, 0);
    acc[0][1] = __builtin_amdgcn_mfma_f32_16x16x32_bf16(
        __builtin_bit_cast(bf16x8, a0), __builtin_bit_cast(bf16x8, b1), acc[0][1], 0, 0, 0);
    acc[1][0] = __builtin_amdgcn_mfma_f32_16x16x32_bf16(
        __builtin_bit_cast(bf16x8, a1), __builtin_bit_cast(bf16x8, b0), acc[1][0], 0, 0, 0);
    acc[1][1] = __builtin_amdgcn_mfma_f32_16x16x32_bf16(
        __builtin_bit_cast(bf16x8, a1), __builtin_bit_cast(bf16x8, b1), acc[1][1], 0, 0, 0);
    if (pf && tid < 256) {
      ushort4 b; b.x = f2b(av.x); b.y = f2b(av.y); b.z = f2b(av.z); b.w = f2b(av.w);
      *(ushort4*)&Asm[cur ^ 1][awoff] = b;
    }
    cur ^= 1;
  }

#pragma unroll
  for (int m = 0; m < 2; ++m)
#pragma unroll
    for (int n = 0; n < 2; ++n) {
      const int col = w * 32 + n * 16 + fr;
      const float bv = bias[col];
#pragma unroll
      for (int r = 0; r < 4; ++r) {
        const int row = m0 + m * 16 + (lane >> 4) * 4 + r;
        float x = acc[m][n][r] + bv;
        x = fmaxf(x, 0.f);
        C[(size_t)row * DDIM + col] = x;
      }
    }
}

extern "C" void kernel_launch(void* const* d_in, const int* in_sizes, int n_in,
                              void* d_out, int out_size, void* d_ws, size_t ws_size,
                              hipStream_t stream) {
  const float* x      = (const float*)d_in[0];
  const float* adj    = (const float*)d_in[1];
  const float* weight = (const float*)d_in[2];
  const float* bias   = (const float*)d_in[3];
  float* out = (float*)d_out;

  char* ws = (char*)d_ws;
  const size_t ab_bytes = (size_t)NROWS * NROWS * 2;     // 128 MB bf16 A
  const size_t h_bytes  = 4ull * NROWS * DDIM * 4;       // 32 MB: 4 k-split partials
  const size_t yt_bytes = (size_t)DDIM * NROWS * 2;      // 4 MB
  const size_t wt_bytes = (size_t)DDIM * DDIM * 2;       // 128 KB
  ushort* Ab      = (ushort*)ws;
  float*  hpart   = (float*)(ws + ab_bytes);
  ushort* Yt      = (ushort*)(ws + ab_bytes + h_bytes);
  ushort* Wt      = (ushort*)(ws + ab_bytes + h_bytes + yt_bytes);
  float*  inv_deg = (float*)(ws + ab_bytes + h_bytes + yt_bytes + wt_bytes);
  const size_t need = ab_bytes + h_bytes + yt_bytes + wt_bytes + (size_t)NROWS * 4;
  if (ws_size < need) { fprintf(stderr, "ws too small: %zu < %zu\n", ws_size, need); return; }

  // k1: degrees + bf16 cast of A (nt loads keep Ab in L3)
  degree_cast_kernel<<<NROWS / 4, 256, 0, stream>>>(adj, Ab, inv_deg);
  // k2 (merged): Yt = bf16(x^T * inv_deg), Wt = bf16(W^T)
  transpose_scale_kernel<<<128 + DDIM / 64, 256, 0, stream>>>(x, weight, inv_deg, Yt, Wt);
  // k3: hpart[ks] = inv_deg * (Ab @ Yt^T) over k-quarter ks (512 blocks = 2/CU resident)
  gemm_big_kernel<<<dim3(512), 256, 0, stream>>>(Ab, Yt, inv_deg, hpart);
  // k4: out = relu((sum of 4 partials) @ Wt^T + bias)
  gemm_small_kernel<<<dim3(256), 512, 0, stream>>>(hpart, Wt, bias, out);
}